// Round 14
// baseline (188.503 us; speedup 1.0000x reference)
//
#include <hip/hip_runtime.h>
#include <stdint.h>

// ---------------------------------------------------------------------------
// NRI-style graph block, v14: REGISTER-RESIDENT rank-1 edge MLP.
// v13 proved rank-1 factoring (128us). v14 removes k1's LDS+barriers entirely:
// wave = (kap, b, slot-quarter), loops 16 receivers. P-quarter in regs
// (frag-major, loaded once), Q[n] broadcast loads, h1 built IN REGISTERS in
// MFMA B-frag layout, W2 A-frags from L1-resident frag-major global.
// Gate -> 4-step shuffle reduce -> fire-and-forget atomicAdd.
//   K0 : weight converts + frag-major W2 + agg zero
//   kPQ: P (frag-major) / Q (linear) per (b,kap,node) via MFMA
//   K1 : GEMM2-only, zero LDS, zero barriers
//   K3 : node MLP split-bf16 (hi+lo 3-term MFMA) + residual
// ---------------------------------------------------------------------------

typedef __attribute__((ext_vector_type(8))) __bf16 bf16x8;
typedef __attribute__((ext_vector_type(4))) float  f32x4;

#define MFMA16(a, b, c) __builtin_amdgcn_mfma_f32_16x16x32_bf16((a), (b), (c), 0, 0, 0)

union U64q { unsigned long long u; __bf16 q[4]; };

static __device__ __forceinline__ unsigned short bfb(__bf16 x) {
  union { __bf16 b; unsigned short u; } c; c.b = x; return c.u;
}

// ---- ws layout (bytes) ----
#define WS_W1    0          // [4][256][128] bf16 (262144)  (kPQ source)
#define WS_O1H   262144     // [256][128] bf16 hi (65536)
#define WS_O1L   327680
#define WS_O2H   393216     // [256][256] bf16 (131072)
#define WS_O2L   524288
#define WS_O3H   655360     // [64][256] bf16 (32768)
#define WS_O3L   688128
#define WS_AGG   720896     // [B*N][64] f32 (1048576) -- atomic target
#define WS_W2F   1769472    // frag-major W2 [4][4 ft][8 kw][64 lane][8] (131072)
#define WS_PF    1900544    // frag-major P [b][kap][q][8 kc2][64 lane][8] (8388608)
#define WS_Q     10289152   // linear Q [b][kap][n][256] bf16 (8388608)
#define WS_NEED  18677760   // ~17.8 MB

// ===========================================================================
// K0: weight conversion + frag-major W2 + agg zero. 573440 items, 2240 blocks.
// ===========================================================================
__global__ __launch_bounds__(256) void k0_convert(
    const float* __restrict__ W1, const float* __restrict__ W2,
    const float* __restrict__ Wo1, const float* __restrict__ Wo2,
    const float* __restrict__ Wo3, char* __restrict__ ws) {
  int i = blockIdx.x * 256 + threadIdx.x;
  if (i < 131072) { ((__bf16*)(ws + WS_W1))[i] = (__bf16)W1[i]; return; }
  i -= 131072;
  if (i < 32768) { float v = Wo1[i]; __bf16 h = (__bf16)v;
    ((__bf16*)(ws + WS_O1H))[i] = h; ((__bf16*)(ws + WS_O1L))[i] = (__bf16)(v - (float)h); return; }
  i -= 32768;
  if (i < 65536) { float v = Wo2[i]; __bf16 h = (__bf16)v;
    ((__bf16*)(ws + WS_O2H))[i] = h; ((__bf16*)(ws + WS_O2L))[i] = (__bf16)(v - (float)h); return; }
  i -= 65536;
  if (i < 16384) { float v = Wo3[i]; __bf16 h = (__bf16)v;
    ((__bf16*)(ws + WS_O3H))[i] = h; ((__bf16*)(ws + WS_O3L))[i] = (__bf16)(v - (float)h); return; }
  i -= 16384;
  if (i < 262144) { ((float*)(ws + WS_AGG))[i] = 0.f; return; }
  i -= 262144;
  if (i < 65536) {   // W2F: lane l holds feat=ft*16+(l&15), k=kw*32+(l>>4)*8+j
    int j = i & 7, lane = (i >> 3) & 63, kw = (i >> 9) & 7, ft = (i >> 12) & 3, kap = i >> 14;
    int feat = ft * 16 + (lane & 15);
    int k = kw * 32 + ((lane >> 4) << 3) + j;
    ((__bf16*)(ws + WS_W2F))[i] = (__bf16)W2[(kap * 64 + feat) * 256 + k];
    return;
  }
}

// ===========================================================================
// kPQ: P[b][kap][s][:] = W1send[kap]@x_s (FRAG-MAJOR out);
//      Q[b][kap][n][:] = W1recv[kap]@x_n + b1 (linear out).
// grid = 64 b x 2 (isP). 256 thr; wave w = kap.
// ===========================================================================
__global__ __launch_bounds__(256) void kPQ(
    const float* __restrict__ inputs, const float* __restrict__ b1g,
    const char* __restrict__ wsr, char* __restrict__ ws) {
  const int b = blockIdx.x >> 1;
  const int isP = blockIdx.x & 1;
  const int tid = threadIdx.x, l = tid & 63, w = tid >> 6;  // w = kap
  const int lg = l >> 4, lr = l & 15;

  bf16x8 bfr[4][2];
#pragma unroll
  for (int nt = 0; nt < 4; ++nt)
#pragma unroll
    for (int kc = 0; kc < 2; ++kc) {
      const float* p = inputs + ((size_t)b * 64 + nt * 16 + lr) * 64 + kc * 32 + lg * 8;
      f32x4 v0 = *(const f32x4*)p, v1 = *(const f32x4*)(p + 4);
      bf16x8 t;
#pragma unroll
      for (int j = 0; j < 4; ++j) { t[j] = (__bf16)v0[j]; t[4 + j] = (__bf16)v1[j]; }
      bfr[nt][kc] = t;
    }

  const char* w1 = wsr + WS_W1 + (isP ? 128 : 0);   // send half at +128B
#pragma unroll 1
  for (int cb = 0; cb < 4; ++cb) {
    f32x4 acc[4][4] = {};
#pragma unroll
    for (int kc = 0; kc < 2; ++kc)
#pragma unroll
      for (int mt = 0; mt < 4; ++mt) {
        int col = w * 256 + cb * 64 + mt * 16 + lr;      // global W1 row
        bf16x8 af = *(const bf16x8*)(w1 + (col << 8) + kc * 64 + (lg << 4));
#pragma unroll
        for (int nt = 0; nt < 4; ++nt)
          acc[mt][nt] = MFMA16(af, bfr[nt][kc], acc[mt][nt]);
      }
#pragma unroll
    for (int mt = 0; mt < 4; ++mt) {
      int col0 = cb * 64 + mt * 16 + (lg << 2);
#pragma unroll
      for (int nt = 0; nt < 4; ++nt) {
        if (isP) {
          // frag-major: elem (s = nt*16+lr, c = col0 + i2)
          U64q pk;
#pragma unroll
          for (int i2 = 0; i2 < 4; ++i2) pk.q[i2] = (__bf16)acc[mt][nt][i2];
          int kc2 = cb * 2 + (mt >> 1);
          int lgc = (mt & 1) * 2 + (lg >> 1);
          int lane = lgc * 16 + lr;
          char* dst = ws + WS_PF + ((((size_t)(b * 4 + w)) * 4 + nt) * 8 + kc2) * 1024
                      + lane * 16 + (lg & 1) * 8;
          *(unsigned long long*)dst = pk.u;
        } else {
          f32x4 bv = *(const f32x4*)(b1g + w * 256 + col0);
          int r = nt * 16 + lr;
          U64q pk;
#pragma unroll
          for (int i2 = 0; i2 < 4; ++i2) pk.q[i2] = (__bf16)(acc[mt][nt][i2] + bv[i2]);
          *(unsigned long long*)(ws + WS_Q + ((((size_t)b * 4 + w) * 64 + r) * 256 + col0) * 2) = pk.u;
        }
      }
    }
  }
}

// ===========================================================================
// K1 v14: wave = (kap, b, slot-quarter q), iterates 16 receivers.
// Zero LDS, zero barriers. P-quarter in regs (frag-major, coalesced, 1x);
// Q[n] broadcast; hb = relu(P+Q) in B-frag layout; W2F A-frags from L1;
// gate by rel_type; shuffle-reduce over 16 slots; atomicAdd agg[b,n,:].
// grid 1024 XCD-affine (bid%8 == b%8); block 256 = 4 waves (quarters).
// ===========================================================================
__global__ __launch_bounds__(256) void k1_edge(
    const float* __restrict__ rel_type, const float* __restrict__ b2g,
    const char* __restrict__ wsr, float* __restrict__ agg) {
  const int tid = threadIdx.x;
  const int bid = blockIdx.x;
  // bid = ((kap*8 + b_hi)*4 + j)*8 + b_lo
  const int b_lo = bid & 7;
  int t = bid >> 3;
  const int jg = t & 3; t >>= 2;
  const int b_hi = t & 7;
  const int kap = t >> 3;
  const int b = b_hi * 8 + b_lo;
  const int n0 = jg * 16;

  const int l = tid & 63, w = tid >> 6;   // w = slot-quarter
  const int lg = l >> 4, lr = l & 15;
  const int s = w * 16 + lr;              // this lane's sender slot

  const char* w2f = wsr + WS_W2F + kap * 32768;                 // [ft][kc2][64][16B]
  const char* Pf  = wsr + WS_PF + (((size_t)(b * 4 + kap)) * 4 + w) * 8192;
  const char* Qb  = wsr + WS_Q + ((size_t)(b * 4 + kap)) * 32768;

  // ---- P-quarter fragments: 8 x 16B, lane-contiguous (coalesced), once ----
  bf16x8 Pr[8];
#pragma unroll
  for (int kc2 = 0; kc2 < 8; ++kc2)
    Pr[kc2] = *(const bf16x8*)(Pf + kc2 * 1024 + l * 16);

#pragma unroll 1
  for (int u = 0; u < 16; ++u) {
    const int n = n0 + u;

    // Q[n] fragments: 8 x 16B broadcast (same addr across lr)
    bf16x8 Qr[8];
#pragma unroll
    for (int kc2 = 0; kc2 < 8; ++kc2)
      Qr[kc2] = *(const bf16x8*)(Qb + n * 512 + kc2 * 64 + lg * 16);

    // rel_type gate (self-slot -> 0)
    float rt;
    if (s == n) rt = 0.f;
    else {
      int e = n * 63 + (s > n ? s - 1 : s);
      rt = rel_type[(((size_t)b * 4032) + e) * 4 + kap];
    }

    // ---- G2: h2[feat][s] over K=256, h1 built in-register per kc2 ----
    f32x4 acc[4] = {};
#pragma unroll
    for (int kc2 = 0; kc2 < 8; ++kc2) {
      bf16x8 hb;
#pragma unroll
      for (int j8 = 0; j8 < 8; ++j8)
        hb[j8] = (__bf16)fmaxf((float)Pr[kc2][j8] + (float)Qr[kc2][j8], 0.f);
#pragma unroll
      for (int ft = 0; ft < 4; ++ft) {
        bf16x8 a2 = *(const bf16x8*)(w2f + ((ft * 8 + kc2) * 64 + l) * 16);
        acc[ft] = MFMA16(a2, hb, acc[ft]);
      }
    }

    // ---- gate + b2 + reduce over 16 slots -> atomicAdd agg[b,n,:] ----
    float sred[4][4];
#pragma unroll
    for (int ft = 0; ft < 4; ++ft) {
      f32x4 bv = *(const f32x4*)(b2g + kap * 64 + ft * 16 + (lg << 2));
#pragma unroll
      for (int i2 = 0; i2 < 4; ++i2)
        sred[ft][i2] = fmaxf(acc[ft][i2] + bv[i2], 0.f) * rt;
    }
#pragma unroll
    for (int mask = 1; mask < 16; mask <<= 1)
#pragma unroll
      for (int ft = 0; ft < 4; ++ft)
#pragma unroll
        for (int i2 = 0; i2 < 4; ++i2)
          sred[ft][i2] += __shfl_xor(sred[ft][i2], mask);

    if (lr == 0) {
      float* dst = agg + ((size_t)b * 64 + n) * 64 + (lg << 2);
#pragma unroll
      for (int ft = 0; ft < 4; ++ft)
#pragma unroll
        for (int i2 = 0; i2 < 4; ++i2)
          atomicAdd(dst + ft * 16 + i2, sred[ft][i2]);
    }
  }
}

// ===========================================================================
// K3: node MLP with split-bf16 (hi+lo) 3-term MFMA + residual
// ===========================================================================
__global__ __launch_bounds__(256) void k3_node(
    const float* __restrict__ inputs, const float* __restrict__ agg,
    const char* __restrict__ wsr,
    const float* __restrict__ bo1, const float* __restrict__ bo2,
    const float* __restrict__ bo3, float* __restrict__ out) {
  __shared__ char sm[65536];
  char* augHi = sm;                  // [32][128] bf16 swz
  char* augLo = sm + 8192;
  char* h1hi  = sm + 16384;          // [32][256] bf16 swz
  char* h1lo  = sm + 32768;
  char* h2hi  = sm;                  // reuse aug region after GEMM1
  char* h2lo  = sm + 49152;

  const char* o1h = wsr + WS_O1H;
  const char* o1l = wsr + WS_O1L;
  const char* o2h = wsr + WS_O2H;
  const char* o2l = wsr + WS_O2L;
  const char* o3h = wsr + WS_O3H;
  const char* o3l = wsr + WS_O3L;

  const int tid = threadIdx.x;
  const int l = tid & 63;
  const int w = tid >> 6;
  const int lg = l >> 4, lr = l & 15;
  const int r0 = blockIdx.x * 32;

  for (int it = 0; it < 8; ++it) {
    int u = tid + it * 256;
    int row = u >> 6, up = u & 63;
    int col = up * 2;
    const float* src = (col < 64) ? (inputs + (r0 + row) * 64 + col)
                                  : (agg + (r0 + row) * 64 + (col - 64));
    float2 v = *(const float2*)src;
    __bf16 h0 = (__bf16)v.x, h1v = (__bf16)v.y;
    __bf16 l0 = (__bf16)(v.x - (float)h0), l1 = (__bf16)(v.y - (float)h1v);
    int off = (row * 256 + col * 2) ^ ((row & 7) << 4);
    ushort2 ph; ph.x = bfb(h0); ph.y = bfb(h1v);
    ushort2 pl; pl.x = bfb(l0); pl.y = bfb(l1);
    *(ushort2*)(augHi + off) = ph;
    *(ushort2*)(augLo + off) = pl;
  }
  __syncthreads();

  f32x4 acc[4][2] = {};
#pragma unroll
  for (int kk = 0; kk < 4; ++kk) {
    bf16x8 ah[4], al[4], bh[2], bl[2];
#pragma unroll
    for (int mfi = 0; mfi < 4; ++mfi) {
      int colp = w * 64 + mfi * 16 + lr;
      int gb = colp * 256 + kk * 64 + (lg << 4);
      ah[mfi] = *(const bf16x8*)(o1h + gb);
      al[mfi] = *(const bf16x8*)(o1l + gb);
    }
#pragma unroll
    for (int nfi = 0; nfi < 2; ++nfi) {
      int row = nfi * 16 + lr;
      int off = (row * 256 + kk * 64 + (lg << 4)) ^ ((row & 7) << 4);
      bh[nfi] = *(const bf16x8*)(augHi + off);
      bl[nfi] = *(const bf16x8*)(augLo + off);
    }
#pragma unroll
    for (int mfi = 0; mfi < 4; ++mfi)
#pragma unroll
      for (int nfi = 0; nfi < 2; ++nfi) {
        acc[mfi][nfi] = MFMA16(ah[mfi], bh[nfi], acc[mfi][nfi]);
        acc[mfi][nfi] = MFMA16(ah[mfi], bl[nfi], acc[mfi][nfi]);
        acc[mfi][nfi] = MFMA16(al[mfi], bh[nfi], acc[mfi][nfi]);
      }
  }
#pragma unroll
  for (int mfi = 0; mfi < 4; ++mfi) {
    int col0 = w * 64 + mfi * 16 + (lg << 2);
    f32x4 bv = *(const f32x4*)(bo1 + col0);
#pragma unroll
    for (int nfi = 0; nfi < 2; ++nfi) {
      int row = nfi * 16 + lr;
      U64q ph, pl;
#pragma unroll
      for (int i2 = 0; i2 < 4; ++i2) {
        float x = fmaxf(acc[mfi][nfi][i2] + bv[i2], 0.f);
        ph.q[i2] = (__bf16)x;
        pl.q[i2] = (__bf16)(x - (float)ph.q[i2]);
      }
      int off = (row * 512 + col0 * 2) ^ ((row & 7) << 4);
      *(unsigned long long*)(h1hi + off) = ph.u;
      *(unsigned long long*)(h1lo + off) = pl.u;
    }
  }
  __syncthreads();

  f32x4 acc2[4][2] = {};
#pragma unroll
  for (int kk = 0; kk < 8; ++kk) {
    bf16x8 ah[4], al[4], bh[2], bl[2];
#pragma unroll
    for (int mfi = 0; mfi < 4; ++mfi) {
      int colp = w * 64 + mfi * 16 + lr;
      int gb = colp * 512 + kk * 64 + (lg << 4);
      ah[mfi] = *(const bf16x8*)(o2h + gb);
      al[mfi] = *(const bf16x8*)(o2l + gb);
    }
#pragma unroll
    for (int nfi = 0; nfi < 2; ++nfi) {
      int row = nfi * 16 + lr;
      int off = (row * 512 + kk * 64 + (lg << 4)) ^ ((row & 7) << 4);
      bh[nfi] = *(const bf16x8*)(h1hi + off);
      bl[nfi] = *(const bf16x8*)(h1lo + off);
    }
#pragma unroll
    for (int mfi = 0; mfi < 4; ++mfi)
#pragma unroll
      for (int nfi = 0; nfi < 2; ++nfi) {
        acc2[mfi][nfi] = MFMA16(ah[mfi], bh[nfi], acc2[mfi][nfi]);
        acc2[mfi][nfi] = MFMA16(ah[mfi], bl[nfi], acc2[mfi][nfi]);
        acc2[mfi][nfi] = MFMA16(al[mfi], bh[nfi], acc2[mfi][nfi]);
      }
  }
#pragma unroll
  for (int mfi = 0; mfi < 4; ++mfi) {
    int col0 = w * 64 + mfi * 16 + (lg << 2);
    f32x4 bv = *(const f32x4*)(bo2 + col0);
#pragma unroll
    for (int nfi = 0; nfi < 2; ++nfi) {
      int row = nfi * 16 + lr;
      U64q ph, pl;
#pragma unroll
      for (int i2 = 0; i2 < 4; ++i2) {
        float x = fmaxf(acc2[mfi][nfi][i2] + bv[i2], 0.f);
        ph.q[i2] = (__bf16)x;
        pl.q[i2] = (__bf16)(x - (float)ph.q[i2]);
      }
      int off = (row * 512 + col0 * 2) ^ ((row & 7) << 4);
      *(unsigned long long*)(h2hi + off) = ph.u;
      *(unsigned long long*)(h2lo + off) = pl.u;
    }
  }
  __syncthreads();

  f32x4 acc3[2] = {};
#pragma unroll
  for (int kk = 0; kk < 8; ++kk) {
    int colp = w * 16 + lr;
    int gb = colp * 512 + kk * 64 + (lg << 4);
    bf16x8 a3h = *(const bf16x8*)(o3h + gb);
    bf16x8 a3l = *(const bf16x8*)(o3l + gb);
#pragma unroll
    for (int nfi = 0; nfi < 2; ++nfi) {
      int row = nfi * 16 + lr;
      int off = (row * 512 + kk * 64 + (lg << 4)) ^ ((row & 7) << 4);
      bf16x8 b3h = *(const bf16x8*)(h2hi + off);
      bf16x8 b3l = *(const bf16x8*)(h2lo + off);
      acc3[nfi] = MFMA16(a3h, b3h, acc3[nfi]);
      acc3[nfi] = MFMA16(a3h, b3l, acc3[nfi]);
      acc3[nfi] = MFMA16(a3l, b3h, acc3[nfi]);
    }
  }
#pragma unroll
  for (int nfi = 0; nfi < 2; ++nfi) {
    int row = nfi * 16 + lr;
    int col0 = w * 16 + (lg << 2);
    f32x4 bv = *(const f32x4*)(bo3 + col0);
    f32x4 iv = *(const f32x4*)(inputs + (r0 + row) * 64 + col0);
    f32x4 o;
#pragma unroll
    for (int i2 = 0; i2 < 4; ++i2) o[i2] = acc3[nfi][i2] + bv[i2] + iv[i2];
    *(f32x4*)(out + (r0 + row) * 64 + col0) = o;
  }
}

// ===========================================================================
extern "C" void kernel_launch(void* const* d_in, const int* in_sizes, int n_in,
                              void* d_out, int out_size, void* d_ws, size_t ws_size,
                              hipStream_t stream) {
  (void)in_sizes; (void)n_in; (void)out_size;
  if (ws_size < (size_t)WS_NEED) return;  // ~17.8 MB

  const float* inputs   = (const float*)d_in[0];
  const float* rel_type = (const float*)d_in[1];
  const float* W1  = (const float*)d_in[4];
  const float* b1  = (const float*)d_in[5];
  const float* W2  = (const float*)d_in[6];
  const float* b2  = (const float*)d_in[7];
  const float* Wo1 = (const float*)d_in[8];
  const float* bo1 = (const float*)d_in[9];
  const float* Wo2 = (const float*)d_in[10];
  const float* bo2 = (const float*)d_in[11];
  const float* Wo3 = (const float*)d_in[12];
  const float* bo3 = (const float*)d_in[13];

  char* ws = (char*)d_ws;
  float* agg = (float*)(ws + WS_AGG);
  float* out = (float*)d_out;

  k0_convert<<<dim3(2240), dim3(256), 0, stream>>>(W1, W2, Wo1, Wo2, Wo3, ws);
  kPQ<<<dim3(128), dim3(256), 0, stream>>>(inputs, b1, ws, ws);
  k1_edge<<<dim3(1024), dim3(256), 0, stream>>>(rel_type, b2, ws, agg);
  k3_node<<<dim3(128), dim3(256), 0, stream>>>(inputs, agg, ws, bo1, bo2, bo3, out);
}

// Round 15
// 124.559 us; speedup vs baseline: 1.5134x; 1.5134x over previous
//
#include <hip/hip_runtime.h>
#include <stdint.h>

// ---------------------------------------------------------------------------
// NRI-style graph block, v15: v13 rank-1 structure + RACE-FREE PLAIN STORES.
// R14 showed agg atomics are the k1 bound (32-64MB HBM write-through from
// cross-XCD line ping-pong). v15: per-kap partial buffers aggp[4][b][n][64],
// unique writer per word, plain f32x4 stores; wn-pair reduce via 256B LDS
// exchange folded into the existing 2-barrier/unit schedule. k3 sums the 4
// partials during aug staging. No atomics anywhere; no agg zeroing.
//   K0 : weight converts + frag-major W2 (no agg pass)
//   kPQ: P/Q per (b,kap,node) via MFMA (rank-1 factors, v13-verified)
//   K1 : GEMM2-only edge MLP -> aggp partials
//   K3 : node MLP split-bf16 (hi+lo 3-term MFMA) + residual; sums aggp
// ---------------------------------------------------------------------------

typedef __attribute__((ext_vector_type(8))) __bf16 bf16x8;
typedef __attribute__((ext_vector_type(4))) float  f32x4;

#define MFMA16(a, b, c) __builtin_amdgcn_mfma_f32_16x16x32_bf16((a), (b), (c), 0, 0, 0)

union U64q { unsigned long long u; __bf16 q[4]; };

static __device__ __forceinline__ unsigned short bfb(__bf16 x) {
  union { __bf16 b; unsigned short u; } c; c.b = x; return c.u;
}

// ---- ws layout (bytes) ----
#define WS_W1    0          // [4][256][128] bf16 (262144)  (kPQ source)
#define WS_O1H   262144     // [256][128] bf16 hi (65536)
#define WS_O1L   327680
#define WS_O2H   393216     // [256][256] bf16 (131072)
#define WS_O2L   524288
#define WS_O3H   655360     // [64][256] bf16 (32768)
#define WS_O3L   688128
#define WS_W2F   720896     // frag-major W2 [4][4 ft][8 kw][64 lane][8] (131072)
#define WS_P     851968     // [b][kap][s][256] bf16 (8388608)
#define WS_Q     9240576    // [b][kap][n][256] bf16 (8388608)
#define WS_AGGP  17629184   // [4 kap][b*64+n][64] f32 (4194304) plain stores
#define WS_NEED  21823488   // ~20.8 MB

// ===========================================================================
// K0: weight conversion + frag-major W2. 311296 items = 1216 blocks x 256.
// ===========================================================================
__global__ __launch_bounds__(256) void k0_convert(
    const float* __restrict__ W1, const float* __restrict__ W2,
    const float* __restrict__ Wo1, const float* __restrict__ Wo2,
    const float* __restrict__ Wo3, char* __restrict__ ws) {
  int i = blockIdx.x * 256 + threadIdx.x;
  if (i < 131072) { ((__bf16*)(ws + WS_W1))[i] = (__bf16)W1[i]; return; }
  i -= 131072;
  if (i < 32768) { float v = Wo1[i]; __bf16 h = (__bf16)v;
    ((__bf16*)(ws + WS_O1H))[i] = h; ((__bf16*)(ws + WS_O1L))[i] = (__bf16)(v - (float)h); return; }
  i -= 32768;
  if (i < 65536) { float v = Wo2[i]; __bf16 h = (__bf16)v;
    ((__bf16*)(ws + WS_O2H))[i] = h; ((__bf16*)(ws + WS_O2L))[i] = (__bf16)(v - (float)h); return; }
  i -= 65536;
  if (i < 16384) { float v = Wo3[i]; __bf16 h = (__bf16)v;
    ((__bf16*)(ws + WS_O3H))[i] = h; ((__bf16*)(ws + WS_O3L))[i] = (__bf16)(v - (float)h); return; }
  i -= 16384;
  if (i < 65536) {   // W2F: lane l holds feat=ft*16+(l&15), k=kw*32+(l>>4)*8+j
    int j = i & 7, lane = (i >> 3) & 63, kw = (i >> 9) & 7, ft = (i >> 12) & 3, kap = i >> 14;
    int feat = ft * 16 + (lane & 15);
    int k = kw * 32 + ((lane >> 4) << 3) + j;
    ((__bf16*)(ws + WS_W2F))[i] = (__bf16)W2[(kap * 64 + feat) * 256 + k];
    return;
  }
}

// ===========================================================================
// kPQ: P[b][kap][s][:] = W1send[kap]@x_s ; Q[b][kap][n][:] = W1recv[kap]@x_n+b1
// grid = 64 b x 2 (isP). 256 thr; wave w = kap. (verified R13)
// ===========================================================================
__global__ __launch_bounds__(256) void kPQ(
    const float* __restrict__ inputs, const float* __restrict__ b1g,
    const char* __restrict__ wsr, char* __restrict__ ws) {
  const int b = blockIdx.x >> 1;
  const int isP = blockIdx.x & 1;
  const int tid = threadIdx.x, l = tid & 63, w = tid >> 6;  // w = kap
  const int lg = l >> 4, lr = l & 15;

  bf16x8 bfr[4][2];
#pragma unroll
  for (int nt = 0; nt < 4; ++nt)
#pragma unroll
    for (int kc = 0; kc < 2; ++kc) {
      const float* p = inputs + ((size_t)b * 64 + nt * 16 + lr) * 64 + kc * 32 + lg * 8;
      f32x4 v0 = *(const f32x4*)p, v1 = *(const f32x4*)(p + 4);
      bf16x8 t;
#pragma unroll
      for (int j = 0; j < 4; ++j) { t[j] = (__bf16)v0[j]; t[4 + j] = (__bf16)v1[j]; }
      bfr[nt][kc] = t;
    }

  const char* w1 = wsr + WS_W1 + (isP ? 128 : 0);   // send half at +128B
  char* outb = ws + (isP ? WS_P : WS_Q);
#pragma unroll 1
  for (int cb = 0; cb < 4; ++cb) {
    f32x4 acc[4][4] = {};
#pragma unroll
    for (int kc = 0; kc < 2; ++kc)
#pragma unroll
      for (int mt = 0; mt < 4; ++mt) {
        int col = w * 256 + cb * 64 + mt * 16 + lr;      // global W1 row
        bf16x8 af = *(const bf16x8*)(w1 + (col << 8) + kc * 64 + (lg << 4));
#pragma unroll
        for (int nt = 0; nt < 4; ++nt)
          acc[mt][nt] = MFMA16(af, bfr[nt][kc], acc[mt][nt]);
      }
#pragma unroll
    for (int mt = 0; mt < 4; ++mt) {
      int col0 = cb * 64 + mt * 16 + (lg << 2);
      f32x4 bv;
      if (isP) { bv[0] = bv[1] = bv[2] = bv[3] = 0.f; }
      else      bv = *(const f32x4*)(b1g + w * 256 + col0);
#pragma unroll
      for (int nt = 0; nt < 4; ++nt) {
        int r = nt * 16 + lr;
        U64q pk;
#pragma unroll
        for (int i2 = 0; i2 < 4; ++i2) pk.q[i2] = (__bf16)(acc[mt][nt][i2] + bv[i2]);
        *(unsigned long long*)(outb + ((((size_t)b * 4 + w) * 64 + r) * 256 + col0) * 2) = pk.u;
      }
    }
  }
}

// ===========================================================================
// K1 v15: block = (kap, b, 16 receivers), XCD-affine. 256 thr / 4 waves.
// Per unit n: h1S = relu(P + Q[n]) (streamed); syncA; G2 (frag-major W2);
// gate + shuffle-reduce; wn1 -> redS; syncB; wn0 adds + PLAIN store to aggp.
// 2 barriers/unit (unchanged from v13). No atomics.
// ===========================================================================
__global__ __launch_bounds__(256) void k1_edge(
    const float* __restrict__ rel_type, const float* __restrict__ b2g,
    const char* __restrict__ wsr, float* __restrict__ aggp) {
  __shared__ char sm[33024];
  char*  h1S  = sm;                  // [64 s][512B], byte ^= ((s&7)<<4)
  float* redS = (float*)(sm + 32768);  // [64] feats exchange

  const int tid = threadIdx.x;
  const int bid = blockIdx.x;
  // bid = ((kap*8 + b_hi)*4 + g)*8 + b_lo   (XCD-affine: bid%8 == b%8)
  const int b_lo = bid & 7;
  int t = bid >> 3;
  const int g = t & 3; t >>= 2;
  const int b_hi = t & 7;
  const int kap = t >> 3;
  const int b = b_hi * 8 + b_lo;
  const int n0 = g * 16;

  const int l = tid & 63, w = tid >> 6;
  const int lg = l >> 4, lr = l & 15;
  const int wm = w >> 1, wn = w & 1;    // G2 grid: 2m (feat half) x 2n (slot half)

  const char* w2f = wsr + WS_W2F;
  const char* Pb  = wsr + WS_P + ((size_t)(b * 4 + kap)) * 32768;  // [64 s][512B]
  const char* Qb  = wsr + WS_Q + ((size_t)(b * 4 + kap)) * 32768;

  f32x4 bv2[2];
#pragma unroll
  for (int mf2 = 0; mf2 < 2; ++mf2)
    bv2[mf2] = *(const f32x4*)(b2g + kap * 64 + wm * 32 + mf2 * 16 + (lg << 2));

#pragma unroll 1
  for (int u = 0; u < 16; ++u) {
    const int n = n0 + u;
    const char* Qn = Qb + n * 512;

    // rel_type gates (self-slot -> 0); sender s -> edge n*63 + (s - (s>n))
    float rt[2];
#pragma unroll
    for (int nf2 = 0; nf2 < 2; ++nf2) {
      int s = wn * 32 + nf2 * 16 + lr;
      if (s == n) rt[nf2] = 0.f;
      else {
        int e = n * 63 + (s > n ? s - 1 : s);
        rt[nf2] = rel_type[(((size_t)b * 4032) + e) * 4 + kap];
      }
    }

    // ---- h1 build: h1[s][c] = relu(P[s][c] + Q[n][c]), coalesced stream ----
#pragma unroll
    for (int it = 0; it < 8; ++it) {
      int uu = tid + it * 256;          // 0..2047 ; s = uu>>5, c0 = (uu&31)*8
      int s = uu >> 5, c0 = (uu & 31) * 8;
      bf16x8 pv = *(const bf16x8*)(Pb + s * 512 + c0 * 2);
      bf16x8 qv = *(const bf16x8*)(Qn + c0 * 2);
      bf16x8 hv;
#pragma unroll
      for (int j = 0; j < 8; ++j)
        hv[j] = (__bf16)fmaxf((float)pv[j] + (float)qv[j], 0.f);
      *(bf16x8*)(h1S + ((s * 512 + c0 * 2) ^ ((s & 7) << 4))) = hv;
    }
    __syncthreads();   // syncA: h1 ready

    // ---- G2: h2 = W2[kap] @ h1^T (M=64 feats, N=64 slots, K=256) ----
    f32x4 acc2[2][2] = {};
#pragma unroll
    for (int kc2 = 0; kc2 < 8; ++kc2) {
      bf16x8 a2[2], b2f[2];
#pragma unroll
      for (int mf2 = 0; mf2 < 2; ++mf2) {
        int ft = wm * 2 + mf2;
        a2[mf2] = *(const bf16x8*)(w2f + (((kap * 4 + ft) * 8 + kc2) * 512 + l * 8) * 2);
      }
#pragma unroll
      for (int nf2 = 0; nf2 < 2; ++nf2) {
        int s = wn * 32 + nf2 * 16 + lr;
        b2f[nf2] = *(const bf16x8*)(h1S + ((s * 512 + (kc2 * 32 + lg * 8) * 2) ^ ((s & 7) << 4)));
      }
#pragma unroll
      for (int mf2 = 0; mf2 < 2; ++mf2)
#pragma unroll
        for (int nf2 = 0; nf2 < 2; ++nf2)
          acc2[mf2][nf2] = MFMA16(a2[mf2], b2f[nf2], acc2[mf2][nf2]);
    }

    // ---- gate + reduce over this wave's 32 slots ----
    float s[2][4];
#pragma unroll
    for (int mf2 = 0; mf2 < 2; ++mf2)
#pragma unroll
      for (int i2 = 0; i2 < 4; ++i2) {
        float v0 = fmaxf(acc2[mf2][0][i2] + bv2[mf2][i2], 0.f) * rt[0];
        float v1 = fmaxf(acc2[mf2][1][i2] + bv2[mf2][i2], 0.f) * rt[1];
        s[mf2][i2] = v0 + v1;
      }
#pragma unroll
    for (int mask = 1; mask < 16; mask <<= 1)
#pragma unroll
      for (int mf2 = 0; mf2 < 2; ++mf2)
#pragma unroll
        for (int i2 = 0; i2 < 4; ++i2)
          s[mf2][i2] += __shfl_xor(s[mf2][i2], mask);

    // wn1 posts its partial to redS (before syncB)
    if (wn == 1 && lr == 0) {
#pragma unroll
      for (int mf2 = 0; mf2 < 2; ++mf2) {
        f32x4 v; v[0] = s[mf2][0]; v[1] = s[mf2][1]; v[2] = s[mf2][2]; v[3] = s[mf2][3];
        *(f32x4*)(redS + wm * 32 + mf2 * 16 + (lg << 2)) = v;
      }
    }
    __syncthreads();   // syncB: h1 consumed + redS ready

    // wn0 combines and stores plain (unique writer per word)
    if (wn == 0 && lr == 0) {
      float* dst = aggp + (((size_t)kap * 4096) + b * 64 + n) * 64;
#pragma unroll
      for (int mf2 = 0; mf2 < 2; ++mf2) {
        int f0 = wm * 32 + mf2 * 16 + (lg << 2);
        f32x4 o = *(const f32x4*)(redS + f0);
#pragma unroll
        for (int i2 = 0; i2 < 4; ++i2) o[i2] += s[mf2][i2];
        *(f32x4*)(dst + f0) = o;
      }
    }
  }
}

// ===========================================================================
// K3: node MLP with split-bf16 (hi+lo) 3-term MFMA + residual.
// aug staging sums the 4 per-kap aggp slices.
// ===========================================================================
__global__ __launch_bounds__(256) void k3_node(
    const float* __restrict__ inputs, const float* __restrict__ aggp,
    const char* __restrict__ wsr,
    const float* __restrict__ bo1, const float* __restrict__ bo2,
    const float* __restrict__ bo3, float* __restrict__ out) {
  __shared__ char sm[65536];
  char* augHi = sm;                  // [32][128] bf16 swz
  char* augLo = sm + 8192;
  char* h1hi  = sm + 16384;          // [32][256] bf16 swz
  char* h1lo  = sm + 32768;
  char* h2hi  = sm;                  // reuse aug region after GEMM1
  char* h2lo  = sm + 49152;

  const char* o1h = wsr + WS_O1H;
  const char* o1l = wsr + WS_O1L;
  const char* o2h = wsr + WS_O2H;
  const char* o2l = wsr + WS_O2L;
  const char* o3h = wsr + WS_O3H;
  const char* o3l = wsr + WS_O3L;

  const int tid = threadIdx.x;
  const int l = tid & 63;
  const int w = tid >> 6;
  const int lg = l >> 4, lr = l & 15;
  const int r0 = blockIdx.x * 32;

  for (int it = 0; it < 8; ++it) {
    int u = tid + it * 256;
    int row = u >> 6, up = u & 63;
    int col = up * 2;
    int node = r0 + row;
    float2 v;
    if (col < 64) {
      v = *(const float2*)(inputs + node * 64 + col);
    } else {
      int f = col - 64;
      v.x = 0.f; v.y = 0.f;
#pragma unroll
      for (int kap = 0; kap < 4; ++kap) {
        float2 t2 = *(const float2*)(aggp + (((size_t)kap * 4096) + node) * 64 + f);
        v.x += t2.x; v.y += t2.y;
      }
    }
    __bf16 h0 = (__bf16)v.x, h1v = (__bf16)v.y;
    __bf16 l0 = (__bf16)(v.x - (float)h0), l1 = (__bf16)(v.y - (float)h1v);
    int off = (row * 256 + col * 2) ^ ((row & 7) << 4);
    ushort2 ph; ph.x = bfb(h0); ph.y = bfb(h1v);
    ushort2 pl; pl.x = bfb(l0); pl.y = bfb(l1);
    *(ushort2*)(augHi + off) = ph;
    *(ushort2*)(augLo + off) = pl;
  }
  __syncthreads();

  f32x4 acc[4][2] = {};
#pragma unroll
  for (int kk = 0; kk < 4; ++kk) {
    bf16x8 ah[4], al[4], bh[2], bl[2];
#pragma unroll
    for (int mfi = 0; mfi < 4; ++mfi) {
      int colp = w * 64 + mfi * 16 + lr;
      int gb = colp * 256 + kk * 64 + (lg << 4);
      ah[mfi] = *(const bf16x8*)(o1h + gb);
      al[mfi] = *(const bf16x8*)(o1l + gb);
    }
#pragma unroll
    for (int nfi = 0; nfi < 2; ++nfi) {
      int row = nfi * 16 + lr;
      int off = (row * 256 + kk * 64 + (lg << 4)) ^ ((row & 7) << 4);
      bh[nfi] = *(const bf16x8*)(augHi + off);
      bl[nfi] = *(const bf16x8*)(augLo + off);
    }
#pragma unroll
    for (int mfi = 0; mfi < 4; ++mfi)
#pragma unroll
      for (int nfi = 0; nfi < 2; ++nfi) {
        acc[mfi][nfi] = MFMA16(ah[mfi], bh[nfi], acc[mfi][nfi]);
        acc[mfi][nfi] = MFMA16(ah[mfi], bl[nfi], acc[mfi][nfi]);
        acc[mfi][nfi] = MFMA16(al[mfi], bh[nfi], acc[mfi][nfi]);
      }
  }
#pragma unroll
  for (int mfi = 0; mfi < 4; ++mfi) {
    int col0 = w * 64 + mfi * 16 + (lg << 2);
    f32x4 bv = *(const f32x4*)(bo1 + col0);
#pragma unroll
    for (int nfi = 0; nfi < 2; ++nfi) {
      int row = nfi * 16 + lr;
      U64q ph, pl;
#pragma unroll
      for (int i2 = 0; i2 < 4; ++i2) {
        float x = fmaxf(acc[mfi][nfi][i2] + bv[i2], 0.f);
        ph.q[i2] = (__bf16)x;
        pl.q[i2] = (__bf16)(x - (float)ph.q[i2]);
      }
      int off = (row * 512 + col0 * 2) ^ ((row & 7) << 4);
      *(unsigned long long*)(h1hi + off) = ph.u;
      *(unsigned long long*)(h1lo + off) = pl.u;
    }
  }
  __syncthreads();

  f32x4 acc2[4][2] = {};
#pragma unroll
  for (int kk = 0; kk < 8; ++kk) {
    bf16x8 ah[4], al[4], bh[2], bl[2];
#pragma unroll
    for (int mfi = 0; mfi < 4; ++mfi) {
      int colp = w * 64 + mfi * 16 + lr;
      int gb = colp * 512 + kk * 64 + (lg << 4);
      ah[mfi] = *(const bf16x8*)(o2h + gb);
      al[mfi] = *(const bf16x8*)(o2l + gb);
    }
#pragma unroll
    for (int nfi = 0; nfi < 2; ++nfi) {
      int row = nfi * 16 + lr;
      int off = (row * 512 + kk * 64 + (lg << 4)) ^ ((row & 7) << 4);
      bh[nfi] = *(const bf16x8*)(h1hi + off);
      bl[nfi] = *(const bf16x8*)(h1lo + off);
    }
#pragma unroll
    for (int mfi = 0; mfi < 4; ++mfi)
#pragma unroll
      for (int nfi = 0; nfi < 2; ++nfi) {
        acc2[mfi][nfi] = MFMA16(ah[mfi], bh[nfi], acc2[mfi][nfi]);
        acc2[mfi][nfi] = MFMA16(ah[mfi], bl[nfi], acc2[mfi][nfi]);
        acc2[mfi][nfi] = MFMA16(al[mfi], bh[nfi], acc2[mfi][nfi]);
      }
  }
#pragma unroll
  for (int mfi = 0; mfi < 4; ++mfi) {
    int col0 = w * 64 + mfi * 16 + (lg << 2);
    f32x4 bv = *(const f32x4*)(bo2 + col0);
#pragma unroll
    for (int nfi = 0; nfi < 2; ++nfi) {
      int row = nfi * 16 + lr;
      U64q ph, pl;
#pragma unroll
      for (int i2 = 0; i2 < 4; ++i2) {
        float x = fmaxf(acc2[mfi][nfi][i2] + bv[i2], 0.f);
        ph.q[i2] = (__bf16)x;
        pl.q[i2] = (__bf16)(x - (float)ph.q[i2]);
      }
      int off = (row * 512 + col0 * 2) ^ ((row & 7) << 4);
      *(unsigned long long*)(h2hi + off) = ph.u;
      *(unsigned long long*)(h2lo + off) = pl.u;
    }
  }
  __syncthreads();

  f32x4 acc3[2] = {};
#pragma unroll
  for (int kk = 0; kk < 8; ++kk) {
    int colp = w * 16 + lr;
    int gb = colp * 512 + kk * 64 + (lg << 4);
    bf16x8 a3h = *(const bf16x8*)(o3h + gb);
    bf16x8 a3l = *(const bf16x8*)(o3l + gb);
#pragma unroll
    for (int nfi = 0; nfi < 2; ++nfi) {
      int row = nfi * 16 + lr;
      int off = (row * 512 + kk * 64 + (lg << 4)) ^ ((row & 7) << 4);
      bf16x8 b3h = *(const bf16x8*)(h2hi + off);
      bf16x8 b3l = *(const bf16x8*)(h2lo + off);
      acc3[nfi] = MFMA16(a3h, b3h, acc3[nfi]);
      acc3[nfi] = MFMA16(a3h, b3l, acc3[nfi]);
      acc3[nfi] = MFMA16(a3l, b3h, acc3[nfi]);
    }
  }
#pragma unroll
  for (int nfi = 0; nfi < 2; ++nfi) {
    int row = nfi * 16 + lr;
    int col0 = w * 16 + (lg << 2);
    f32x4 bv = *(const f32x4*)(bo3 + col0);
    f32x4 iv = *(const f32x4*)(inputs + (r0 + row) * 64 + col0);
    f32x4 o;
#pragma unroll
    for (int i2 = 0; i2 < 4; ++i2) o[i2] = acc3[nfi][i2] + bv[i2] + iv[i2];
    *(f32x4*)(out + (r0 + row) * 64 + col0) = o;
  }
}

// ===========================================================================
extern "C" void kernel_launch(void* const* d_in, const int* in_sizes, int n_in,
                              void* d_out, int out_size, void* d_ws, size_t ws_size,
                              hipStream_t stream) {
  (void)in_sizes; (void)n_in; (void)out_size;
  if (ws_size < (size_t)WS_NEED) return;  // ~20.8 MB

  const float* inputs   = (const float*)d_in[0];
  const float* rel_type = (const float*)d_in[1];
  const float* W1  = (const float*)d_in[4];
  const float* b1  = (const float*)d_in[5];
  const float* W2  = (const float*)d_in[6];
  const float* b2  = (const float*)d_in[7];
  const float* Wo1 = (const float*)d_in[8];
  const float* bo1 = (const float*)d_in[9];
  const float* Wo2 = (const float*)d_in[10];
  const float* bo2 = (const float*)d_in[11];
  const float* Wo3 = (const float*)d_in[12];
  const float* bo3 = (const float*)d_in[13];

  char* ws = (char*)d_ws;
  float* aggp = (float*)(ws + WS_AGGP);
  float* out  = (float*)d_out;

  k0_convert<<<dim3(1216), dim3(256), 0, stream>>>(W1, W2, Wo1, Wo2, Wo3, ws);
  kPQ<<<dim3(128), dim3(256), 0, stream>>>(inputs, b1, ws, ws);
  k1_edge<<<dim3(1024), dim3(256), 0, stream>>>(rel_type, b2, ws, aggp);
  k3_node<<<dim3(128), dim3(256), 0, stream>>>(inputs, aggp, ws, bo1, bo2, bo3, out);
}